// Round 4
// baseline (340.518 us; speedup 1.0000x reference)
//
#include <hip/hip_runtime.h>

#define T_LEN 512
#define NHID 16
#define NEMB 10
#define VOCAB1 50001

typedef float v2f __attribute__((ext_vector_type(2)));

// ---------------------------------------------------------------------------
// Kernel 1: xproj table, layout [v][16][4] f32: float4 at (v*16+j) =
//   {i,f,g,o} pre-activations for unit j = bih+bhh + emb[v]·Wih rows.
// ---------------------------------------------------------------------------
__global__ __launch_bounds__(256) void build_table(
    const float* __restrict__ emb, const float* __restrict__ Wih,
    const float* __restrict__ bih, const float* __restrict__ bhh,
    float* __restrict__ tbl)
{
    const int tid = blockIdx.x * 256 + threadIdx.x;
    if (tid >= VOCAB1 * 16) return;
    const int v = tid >> 4, j = tid & 15;
    float e[NEMB];
    #pragma unroll
    for (int i = 0; i < NEMB; ++i) e[i] = emb[v * NEMB + i];
    float o[4];
    #pragma unroll
    for (int q = 0; q < 4; ++q) {
        const int r = q * 16 + j;
        float a = bih[r] + bhh[r];
        #pragma unroll
        for (int i = 0; i < NEMB; ++i) a += e[i] * Wih[r * NEMB + i];
        o[q] = a;
    }
    ((float4*)tbl)[tid] = make_float4(o[0], o[1], o[2], o[3]);
}

// ---------------------------------------------------------------------------
// Kernel 2: 16 lanes/batch, ILP=2 — each lane runs TWO independent batch
// chains (A, B) interleaved, so A's LDS round-trip + transcendental latency
// hides under B's compute. 8 batches/wave, 512 waves. hx is wave-private
// (no __syncthreads anywhere). Table loads pipelined 2 iterations deep;
// token indices read directly from global (L1 broadcast, sequential lines).
// ---------------------------------------------------------------------------
__global__ __launch_bounds__(256) void lstm_ilp2_kernel(
    const int*   __restrict__ x,
    const float* __restrict__ tbl,
    const float* __restrict__ Whh,
    const float* __restrict__ Wfc,
    const float* __restrict__ bfc,
    float*       __restrict__ out)
{
    __shared__ float hx[32 * 16];         // [local_batch][unit], wave-private use

    const int tid  = threadIdx.x;
    const int wv   = tid >> 6;
    const int lane = tid & 63;
    const int j    = lane & 15;           // hidden unit owned
    const int g    = lane >> 4;           // group within wave
    const int lbA  = wv * 8 + g;          // local batch A (0..31)
    const int lbB  = lbA + 4;             // local batch B
    const int bA   = blockIdx.x * 32 + lbA;
    const int bB   = blockIdx.x * 32 + lbB;

    // recurrent weights: 4 gate rows for unit j, as float2 pairs (pk_fma)
    v2f w[4][8];
    #pragma unroll
    for (int q = 0; q < 4; ++q) {
        const int r = j + 16 * q;
        #pragma unroll
        for (int p = 0; p < 8; ++p)
            w[q][p] = (v2f){Whh[r * NHID + 2 * p], Whh[r * NHID + 2 * p + 1]};
    }

    v2f hA[8], hB[8];
    #pragma unroll
    for (int p = 0; p < 8; ++p) { hA[p] = (v2f){0.f, 0.f}; hB[p] = (v2f){0.f, 0.f}; }
    float cA = 0.f, cB = 0.f;

    const float NL2E  = -1.44269504088896f;
    const float NL2E2 = -2.88539008177793f;

    const float4* t4  = (const float4*)tbl;
    const float4* hpA = (const float4*)&hx[lbA * 16];
    const float4* hpB = (const float4*)&hx[lbB * 16];
    const int* xA = x + (long)bA * T_LEN;
    const int* xB = x + (long)bB * T_LEN;

    // one full LSTM step for one batch chain; bit-identical math to R2
    auto step = [&](const float4& tb, v2f* h2, float& c) -> float {
        v2f a0 = (v2f){tb.x, 0.f}, a1 = (v2f){tb.y, 0.f};
        v2f a2 = (v2f){tb.z, 0.f}, a3 = (v2f){tb.w, 0.f};
        #pragma unroll
        for (int p = 0; p < 8; ++p) {
            a0 += h2[p] * w[0][p];
            a1 += h2[p] * w[1][p];
            a2 += h2[p] * w[2][p];
            a3 += h2[p] * w[3][p];
        }
        const float vi = a0.x + a0.y, vf = a1.x + a1.y;
        const float vg = a2.x + a2.y, vo = a3.x + a3.y;
        const float ig = __builtin_amdgcn_rcpf(1.f + __builtin_amdgcn_exp2f(vi * NL2E));
        const float fg = __builtin_amdgcn_rcpf(1.f + __builtin_amdgcn_exp2f(vf * NL2E));
        const float gg = 2.f * __builtin_amdgcn_rcpf(1.f + __builtin_amdgcn_exp2f(vg * NL2E2)) - 1.f;
        const float og = __builtin_amdgcn_rcpf(1.f + __builtin_amdgcn_exp2f(vo * NL2E));
        c = fg * c + ig * gg;
        const float tc = 2.f * __builtin_amdgcn_rcpf(1.f + __builtin_amdgcn_exp2f(c * NL2E2)) - 1.f;
        return og * tc;
    };

    // software pipeline, depth 2: tb*(t), tb*(t+1) resident, issue t+2 in-loop
    float4 tA0 = t4[(long)xA[0] * 16 + j];
    float4 tB0 = t4[(long)xB[0] * 16 + j];
    float4 tA1 = t4[(long)xA[1] * 16 + j];
    float4 tB1 = t4[(long)xB[1] * 16 + j];
    int iA2 = xA[2], iB2 = xB[2];

    #pragma unroll 1
    for (int t = 0; t < T_LEN; ++t) {
        // issue loads for t+2 (indices were guarded to 0 when OOB)
        const float4 tA2 = t4[(long)iA2 * 16 + j];
        const float4 tB2 = t4[(long)iB2 * 16 + j];
        const int iA3 = (t + 3 < T_LEN) ? xA[t + 3] : 0;
        const int iB3 = (t + 3 < T_LEN) ? xB[t + 3] : 0;

        // batch A step, write its h; B's compute hides A's LDS round trip
        const float hvA = step(tA0, hA, cA);
        hx[lbA * 16 + j] = hvA;

        const float hvB = step(tB0, hB, cB);
        hx[lbB * 16 + j] = hvB;

        // read back broadcast h vectors (same wave, no barrier)
        const float4 a0 = hpA[0], a1 = hpA[1], a2 = hpA[2], a3 = hpA[3];
        const float4 b0 = hpB[0], b1 = hpB[1], b2 = hpB[2], b3 = hpB[3];
        hA[0] = (v2f){a0.x, a0.y}; hA[1] = (v2f){a0.z, a0.w};
        hA[2] = (v2f){a1.x, a1.y}; hA[3] = (v2f){a1.z, a1.w};
        hA[4] = (v2f){a2.x, a2.y}; hA[5] = (v2f){a2.z, a2.w};
        hA[6] = (v2f){a3.x, a3.y}; hA[7] = (v2f){a3.z, a3.w};
        hB[0] = (v2f){b0.x, b0.y}; hB[1] = (v2f){b0.z, b0.w};
        hB[2] = (v2f){b1.x, b1.y}; hB[3] = (v2f){b1.z, b1.w};
        hB[4] = (v2f){b2.x, b2.y}; hB[5] = (v2f){b2.z, b2.w};
        hB[6] = (v2f){b3.x, b3.y}; hB[7] = (v2f){b3.z, b3.w};

        tA0 = tA1; tA1 = tA2; iA2 = iA3;
        tB0 = tB1; tB1 = tB2; iB2 = iB3;
    }

    if (j == 0) {
        float lgA = bfc[0], lgB = bfc[0];
        #pragma unroll
        for (int p = 0; p < 8; ++p) {
            lgA += hA[p].x * Wfc[2 * p] + hA[p].y * Wfc[2 * p + 1];
            lgB += hB[p].x * Wfc[2 * p] + hB[p].y * Wfc[2 * p + 1];
        }
        out[bA] = __builtin_amdgcn_rcpf(1.f + __builtin_amdgcn_exp2f(lgA * NL2E));
        out[bB] = __builtin_amdgcn_rcpf(1.f + __builtin_amdgcn_exp2f(lgB * NL2E));
    }
}

// ---------------------------------------------------------------------------
// Fallback (ws too small for the 12.8 MB table): R2's 16-lane on-the-fly path.
// ---------------------------------------------------------------------------
__global__ __launch_bounds__(256) void lstm_fb_kernel(
    const int*   __restrict__ x,
    const float* __restrict__ emb,
    const float* __restrict__ Wih,
    const float* __restrict__ Whh,
    const float* __restrict__ bih,
    const float* __restrict__ bhh,
    const float* __restrict__ Wfc,
    const float* __restrict__ bfc,
    float*       __restrict__ out)
{
    __shared__ int   idx_lds[T_LEN][16];
    __shared__ float hx[4 * 64];

    const int tid  = threadIdx.x;
    const int wv   = tid >> 6;
    const int lane = tid & 63;
    const int j    = lane & 15;
    const int g    = lane >> 4;
    const int lb   = tid >> 4;
    const int batch = blockIdx.x * 16 + lb;

    for (int i = tid; i < 16 * T_LEN; i += 256) {
        int b = i >> 9;
        int t = i & (T_LEN - 1);
        idx_lds[t][b] = x[(blockIdx.x * 16 + b) * T_LEN + t];
    }

    float wih[4][NEMB], bias[4];
    v2f w[4][8];
    #pragma unroll
    for (int q = 0; q < 4; ++q) {
        const int r = j + 16 * q;
        #pragma unroll
        for (int e = 0; e < NEMB; ++e) wih[q][e] = Wih[r * NEMB + e];
        #pragma unroll
        for (int p = 0; p < 8; ++p)
            w[q][p] = (v2f){Whh[r * NHID + 2 * p], Whh[r * NHID + 2 * p + 1]};
        bias[q] = bih[r] + bhh[r];
    }

    __syncthreads();

    v2f h2[8];
    #pragma unroll
    for (int p = 0; p < 8; ++p) h2[p] = (v2f){0.f, 0.f};
    float c = 0.f;

    const float NL2E  = -1.44269504088896f;
    const float NL2E2 = -2.88539008177793f;
    const int hxW = wv * 64;
    const float4* hp = (const float4*)&hx[hxW + g * 16];

    float2 xa, xb, xc, xd, xe2;
    {
        const float2* er = (const float2*)(emb + (long)idx_lds[0][lb] * NEMB);
        xa = er[0]; xb = er[1]; xc = er[2]; xd = er[3]; xe2 = er[4];
    }
    int idx_n = idx_lds[1][lb];

    #pragma unroll 1
    for (int t = 0; t < T_LEN; ++t) {
        const float xv[NEMB] = {xa.x, xa.y, xb.x, xb.y, xc.x, xc.y,
                                xd.x, xd.y, xe2.x, xe2.y};
        if (t + 1 < T_LEN) {
            const float2* er = (const float2*)(emb + (long)idx_n * NEMB);
            xa = er[0]; xb = er[1]; xc = er[2]; xd = er[3]; xe2 = er[4];
        }
        const int idx_nn = (t + 2 < T_LEN) ? idx_lds[t + 2][lb] : 0;

        float v[4];
        #pragma unroll
        for (int q = 0; q < 4; ++q) {
            float a = bias[q];
            #pragma unroll
            for (int e = 0; e < NEMB; ++e) a += xv[e] * wih[q][e];
            v[q] = a;
        }
        v2f a0 = (v2f){v[0], 0.f}, a1 = (v2f){v[1], 0.f};
        v2f a2 = (v2f){v[2], 0.f}, a3 = (v2f){v[3], 0.f};
        #pragma unroll
        for (int p = 0; p < 8; ++p) {
            a0 += h2[p] * w[0][p];
            a1 += h2[p] * w[1][p];
            a2 += h2[p] * w[2][p];
            a3 += h2[p] * w[3][p];
        }
        const float vi = a0.x + a0.y, vf = a1.x + a1.y;
        const float vg = a2.x + a2.y, vo = a3.x + a3.y;

        const float ig = __builtin_amdgcn_rcpf(1.f + __builtin_amdgcn_exp2f(vi * NL2E));
        const float fg = __builtin_amdgcn_rcpf(1.f + __builtin_amdgcn_exp2f(vf * NL2E));
        const float gg = 2.f * __builtin_amdgcn_rcpf(1.f + __builtin_amdgcn_exp2f(vg * NL2E2)) - 1.f;
        const float og = __builtin_amdgcn_rcpf(1.f + __builtin_amdgcn_exp2f(vo * NL2E));

        c = fg * c + ig * gg;
        const float tc = 2.f * __builtin_amdgcn_rcpf(1.f + __builtin_amdgcn_exp2f(c * NL2E2)) - 1.f;
        const float hv = og * tc;

        hx[hxW + lane] = hv;
        const float4 b0 = hp[0], b1 = hp[1], b2 = hp[2], b3 = hp[3];
        h2[0] = (v2f){b0.x, b0.y}; h2[1] = (v2f){b0.z, b0.w};
        h2[2] = (v2f){b1.x, b1.y}; h2[3] = (v2f){b1.z, b1.w};
        h2[4] = (v2f){b2.x, b2.y}; h2[5] = (v2f){b2.z, b2.w};
        h2[6] = (v2f){b3.x, b3.y}; h2[7] = (v2f){b3.z, b3.w};

        idx_n = idx_nn;
    }

    if (j == 0) {
        float logit = bfc[0];
        #pragma unroll
        for (int p = 0; p < 8; ++p)
            logit += h2[p].x * Wfc[2 * p] + h2[p].y * Wfc[2 * p + 1];
        out[batch] = __builtin_amdgcn_rcpf(1.f + __builtin_amdgcn_exp2f(logit * NL2E));
    }
}

extern "C" void kernel_launch(void* const* d_in, const int* in_sizes, int n_in,
                              void* d_out, int out_size, void* d_ws, size_t ws_size,
                              hipStream_t stream) {
    const int*   x   = (const int*)  d_in[0];
    const float* emb = (const float*)d_in[1];
    const float* Wih = (const float*)d_in[2];
    const float* Whh = (const float*)d_in[3];
    const float* bih = (const float*)d_in[4];
    const float* bhh = (const float*)d_in[5];
    const float* Wfc = (const float*)d_in[6];
    const float* bfc = (const float*)d_in[7];
    float* outp = (float*)d_out;

    const int B = in_sizes[0] / T_LEN;                               // 4096
    const size_t TABLE_BYTES = (size_t)VOCAB1 * 64 * sizeof(float);  // 12.8 MB

    if (ws_size >= TABLE_BYTES) {
        float* tbl = (float*)d_ws;
        build_table<<<(VOCAB1 * 16 + 255) / 256, 256, 0, stream>>>(emb, Wih, bih, bhh, tbl);
        lstm_ilp2_kernel<<<B / 32, 256, 0, stream>>>(x, tbl, Whh, Wfc, bfc, outp);
    } else {
        lstm_fb_kernel<<<B / 16, 256, 0, stream>>>(x, emb, Wih, Whh, bih, bhh, Wfc, bfc, outp);
    }
}

// Round 5
// 155.060 us; speedup vs baseline: 2.1960x; 2.1960x over previous
//
#include <hip/hip_runtime.h>

#define T_LEN 512
#define NHID 16
#define NEMB 10
#define VOCAB1 50001

typedef float v2f __attribute__((ext_vector_type(2)));

// ---------------------------------------------------------------------------
// Kernel 1: xproj table, layout [v][16][4] f32: float4 at (v*16+j) =
//   {i,f,g,o} pre-activations for unit j = bih+bhh + emb[v]·Wih rows.
// ---------------------------------------------------------------------------
__global__ __launch_bounds__(256) void build_table(
    const float* __restrict__ emb, const float* __restrict__ Wih,
    const float* __restrict__ bih, const float* __restrict__ bhh,
    float* __restrict__ tbl)
{
    const int tid = blockIdx.x * 256 + threadIdx.x;
    if (tid >= VOCAB1 * 16) return;
    const int v = tid >> 4, j = tid & 15;
    float e[NEMB];
    #pragma unroll
    for (int i = 0; i < NEMB; ++i) e[i] = emb[v * NEMB + i];
    float o[4];
    #pragma unroll
    for (int q = 0; q < 4; ++q) {
        const int r = q * 16 + j;
        float a = bih[r] + bhh[r];
        #pragma unroll
        for (int i = 0; i < NEMB; ++i) a += e[i] * Wih[r * NEMB + i];
        o[q] = a;
    }
    ((float4*)tbl)[tid] = make_float4(o[0], o[1], o[2], o[3]);
}

// ---------------------------------------------------------------------------
// Kernel 2: 16 lanes/batch (lane j owns unit j + gate rows {j,j+16,j+32,j+48}),
// 4 batch/wave, 16 batch/block, 1024 waves. DEEP register pipeline for the
// random table-row loads: 4 stages, loop unrolled x4 with compile-time stage
// indices -> no register rotation -> compiler emits counted vmcnt(3), each
// load stays in flight ~4 steps (>1000 cy, covers LLC). Indices in padded LDS
// (vmcnt FIFO stays table-only). hx stride 20 -> conflict-free b128 reads.
// ---------------------------------------------------------------------------
__global__ __launch_bounds__(256) void lstm_pipe_kernel(
    const int*   __restrict__ x,
    const float* __restrict__ tbl,
    const float* __restrict__ Whh,
    const float* __restrict__ Wfc,
    const float* __restrict__ bfc,
    float*       __restrict__ out)
{
    __shared__ int   idx_lds[T_LEN + 8][17];  // [t][batch], pad 17: no bank conflicts
    __shared__ float hx[16][20];              // [batch][unit], stride 20: b128 reads clean

    const int tid  = threadIdx.x;
    const int lane = tid & 63;
    const int j    = lane & 15;          // hidden unit owned
    const int lb   = tid >> 4;           // local batch 0..15
    const int batch = blockIdx.x * 16 + lb;

    // stage indices (t >= T_LEN slots -> token 0, keeps prefetch unguarded)
    for (int i = tid; i < 16 * (T_LEN + 8); i += 256) {
        const int b = i & 15;
        const int t = i >> 4;
        idx_lds[t][b] = (t < T_LEN) ? x[(blockIdx.x * 16 + b) * T_LEN + t] : 0;
    }

    // recurrent weights: 4 gate rows for unit j as float2 pairs (pk_fma)
    v2f w[4][8];
    #pragma unroll
    for (int q = 0; q < 4; ++q) {
        const int r = j + 16 * q;
        #pragma unroll
        for (int p = 0; p < 8; ++p)
            w[q][p] = (v2f){Whh[r * NHID + 2 * p], Whh[r * NHID + 2 * p + 1]};
    }

    __syncthreads();

    v2f h2[8];
    #pragma unroll
    for (int p = 0; p < 8; ++p) h2[p] = (v2f){0.f, 0.f};
    float c = 0.f;

    const float NL2E  = -1.44269504088896f;
    const float NL2E2 = -2.88539008177793f;
    const float4* t4 = (const float4*)tbl;
    const float4* hp = (const float4*)&hx[lb][0];

    // prologue: fill the 4-stage pipeline (rows for t = 0..3)
    float4 pf[4];
    #pragma unroll
    for (int s = 0; s < 4; ++s)
        pf[s] = t4[(long)idx_lds[s][lb] * 16 + j];

    #pragma unroll 1
    for (int t = 0; t < T_LEN; t += 4) {
        #pragma unroll
        for (int u = 0; u < 4; ++u) {
            const float4 tb = pf[u];                       // vmcnt(3) wait here
            // refill stage u with row for t+4+u (idx staged in LDS, t+4+u < T_LEN+8)
            pf[u] = t4[(long)idx_lds[t + 4 + u][lb] * 16 + j];

            // gate pre-activations (bias folded into table)
            v2f a0 = (v2f){tb.x, 0.f}, a1 = (v2f){tb.y, 0.f};
            v2f a2 = (v2f){tb.z, 0.f}, a3 = (v2f){tb.w, 0.f};
            #pragma unroll
            for (int p = 0; p < 8; ++p) {
                a0 += h2[p] * w[0][p];
                a1 += h2[p] * w[1][p];
                a2 += h2[p] * w[2][p];
                a3 += h2[p] * w[3][p];
            }
            const float vi = a0.x + a0.y, vf = a1.x + a1.y;
            const float vg = a2.x + a2.y, vo = a3.x + a3.y;

            const float ig = __builtin_amdgcn_rcpf(1.f + __builtin_amdgcn_exp2f(vi * NL2E));
            const float fg = __builtin_amdgcn_rcpf(1.f + __builtin_amdgcn_exp2f(vf * NL2E));
            const float gg = 2.f * __builtin_amdgcn_rcpf(1.f + __builtin_amdgcn_exp2f(vg * NL2E2)) - 1.f;
            const float og = __builtin_amdgcn_rcpf(1.f + __builtin_amdgcn_exp2f(vo * NL2E));

            c = fg * c + ig * gg;
            const float tc = 2.f * __builtin_amdgcn_rcpf(1.f + __builtin_amdgcn_exp2f(c * NL2E2)) - 1.f;
            const float hv = og * tc;

            // h broadcast: 1 ds_write + 4 ds_read_b128, wave-private (no barrier)
            hx[lb][j] = hv;
            const float4 b0 = hp[0], b1 = hp[1], b2 = hp[2], b3 = hp[3];
            h2[0] = (v2f){b0.x, b0.y}; h2[1] = (v2f){b0.z, b0.w};
            h2[2] = (v2f){b1.x, b1.y}; h2[3] = (v2f){b1.z, b1.w};
            h2[4] = (v2f){b2.x, b2.y}; h2[5] = (v2f){b2.z, b2.w};
            h2[6] = (v2f){b3.x, b3.y}; h2[7] = (v2f){b3.z, b3.w};
        }
    }

    if (j == 0) {
        float logit = bfc[0];
        #pragma unroll
        for (int p = 0; p < 8; ++p)
            logit += h2[p].x * Wfc[2 * p] + h2[p].y * Wfc[2 * p + 1];
        out[batch] = __builtin_amdgcn_rcpf(1.f + __builtin_amdgcn_exp2f(logit * NL2E));
    }
}

// ---------------------------------------------------------------------------
// Fallback (ws too small for the 12.8 MB table): on-the-fly xproj path.
// ---------------------------------------------------------------------------
__global__ __launch_bounds__(256) void lstm_fb_kernel(
    const int*   __restrict__ x,
    const float* __restrict__ emb,
    const float* __restrict__ Wih,
    const float* __restrict__ Whh,
    const float* __restrict__ bih,
    const float* __restrict__ bhh,
    const float* __restrict__ Wfc,
    const float* __restrict__ bfc,
    float*       __restrict__ out)
{
    __shared__ int   idx_lds[T_LEN][17];
    __shared__ float hx[16][20];

    const int tid  = threadIdx.x;
    const int lane = tid & 63;
    const int j    = lane & 15;
    const int lb   = tid >> 4;
    const int batch = blockIdx.x * 16 + lb;

    for (int i = tid; i < 16 * T_LEN; i += 256) {
        const int b = i & 15;
        const int t = i >> 4;
        idx_lds[t][b] = x[(blockIdx.x * 16 + b) * T_LEN + t];
    }

    float wih[4][NEMB], bias[4];
    v2f w[4][8];
    #pragma unroll
    for (int q = 0; q < 4; ++q) {
        const int r = j + 16 * q;
        #pragma unroll
        for (int e = 0; e < NEMB; ++e) wih[q][e] = Wih[r * NEMB + e];
        #pragma unroll
        for (int p = 0; p < 8; ++p)
            w[q][p] = (v2f){Whh[r * NHID + 2 * p], Whh[r * NHID + 2 * p + 1]};
        bias[q] = bih[r] + bhh[r];
    }

    __syncthreads();

    v2f h2[8];
    #pragma unroll
    for (int p = 0; p < 8; ++p) h2[p] = (v2f){0.f, 0.f};
    float c = 0.f;

    const float NL2E  = -1.44269504088896f;
    const float NL2E2 = -2.88539008177793f;
    const float4* hp = (const float4*)&hx[lb][0];

    float2 xa, xb, xc, xd, xe2;
    {
        const float2* er = (const float2*)(emb + (long)idx_lds[0][lb] * NEMB);
        xa = er[0]; xb = er[1]; xc = er[2]; xd = er[3]; xe2 = er[4];
    }
    int idx_n = idx_lds[1][lb];

    #pragma unroll 1
    for (int t = 0; t < T_LEN; ++t) {
        const float xv[NEMB] = {xa.x, xa.y, xb.x, xb.y, xc.x, xc.y,
                                xd.x, xd.y, xe2.x, xe2.y};
        if (t + 1 < T_LEN) {
            const float2* er = (const float2*)(emb + (long)idx_n * NEMB);
            xa = er[0]; xb = er[1]; xc = er[2]; xd = er[3]; xe2 = er[4];
        }
        const int idx_nn = (t + 2 < T_LEN) ? idx_lds[t + 2][lb] : 0;

        float v[4];
        #pragma unroll
        for (int q = 0; q < 4; ++q) {
            float a = bias[q];
            #pragma unroll
            for (int e = 0; e < NEMB; ++e) a += xv[e] * wih[q][e];
            v[q] = a;
        }
        v2f a0 = (v2f){v[0], 0.f}, a1 = (v2f){v[1], 0.f};
        v2f a2 = (v2f){v[2], 0.f}, a3 = (v2f){v[3], 0.f};
        #pragma unroll
        for (int p = 0; p < 8; ++p) {
            a0 += h2[p] * w[0][p];
            a1 += h2[p] * w[1][p];
            a2 += h2[p] * w[2][p];
            a3 += h2[p] * w[3][p];
        }
        const float vi = a0.x + a0.y, vf = a1.x + a1.y;
        const float vg = a2.x + a2.y, vo = a3.x + a3.y;

        const float ig = __builtin_amdgcn_rcpf(1.f + __builtin_amdgcn_exp2f(vi * NL2E));
        const float fg = __builtin_amdgcn_rcpf(1.f + __builtin_amdgcn_exp2f(vf * NL2E));
        const float gg = 2.f * __builtin_amdgcn_rcpf(1.f + __builtin_amdgcn_exp2f(vg * NL2E2)) - 1.f;
        const float og = __builtin_amdgcn_rcpf(1.f + __builtin_amdgcn_exp2f(vo * NL2E));

        c = fg * c + ig * gg;
        const float tc = 2.f * __builtin_amdgcn_rcpf(1.f + __builtin_amdgcn_exp2f(c * NL2E2)) - 1.f;
        const float hv = og * tc;

        hx[lb][j] = hv;
        const float4 b0 = hp[0], b1 = hp[1], b2 = hp[2], b3 = hp[3];
        h2[0] = (v2f){b0.x, b0.y}; h2[1] = (v2f){b0.z, b0.w};
        h2[2] = (v2f){b1.x, b1.y}; h2[3] = (v2f){b1.z, b1.w};
        h2[4] = (v2f){b2.x, b2.y}; h2[5] = (v2f){b2.z, b2.w};
        h2[6] = (v2f){b3.x, b3.y}; h2[7] = (v2f){b3.z, b3.w};

        idx_n = idx_nn;
    }

    if (j == 0) {
        float logit = bfc[0];
        #pragma unroll
        for (int p = 0; p < 8; ++p)
            logit += h2[p].x * Wfc[2 * p] + h2[p].y * Wfc[2 * p + 1];
        out[batch] = __builtin_amdgcn_rcpf(1.f + __builtin_amdgcn_exp2f(logit * NL2E));
    }
}

extern "C" void kernel_launch(void* const* d_in, const int* in_sizes, int n_in,
                              void* d_out, int out_size, void* d_ws, size_t ws_size,
                              hipStream_t stream) {
    const int*   x   = (const int*)  d_in[0];
    const float* emb = (const float*)d_in[1];
    const float* Wih = (const float*)d_in[2];
    const float* Whh = (const float*)d_in[3];
    const float* bih = (const float*)d_in[4];
    const float* bhh = (const float*)d_in[5];
    const float* Wfc = (const float*)d_in[6];
    const float* bfc = (const float*)d_in[7];
    float* outp = (float*)d_out;

    const int B = in_sizes[0] / T_LEN;                               // 4096
    const size_t TABLE_BYTES = (size_t)VOCAB1 * 64 * sizeof(float);  // 12.8 MB

    if (ws_size >= TABLE_BYTES) {
        float* tbl = (float*)d_ws;
        build_table<<<(VOCAB1 * 16 + 255) / 256, 256, 0, stream>>>(emb, Wih, bih, bhh, tbl);
        lstm_pipe_kernel<<<B / 16, 256, 0, stream>>>(x, tbl, Whh, Wfc, bfc, outp);
    } else {
        lstm_fb_kernel<<<B / 16, 256, 0, stream>>>(x, emb, Wih, Whh, bih, bhh, Wfc, bfc, outp);
    }
}